// Round 1
// baseline (523.200 us; speedup 1.0000x reference)
//
#include <hip/hip_runtime.h>

#define NDIM 512
#define CZ 128
#define NN (NDIM*NDIM)

typedef __attribute__((ext_vector_type(8))) short short8;
typedef __attribute__((ext_vector_type(4))) float f32x4;
typedef unsigned short ushort_t;

__device__ __forceinline__ ushort_t f2b(float f) {
  unsigned int x = __float_as_uint(f);
  unsigned int r = (x + 0x7fffu + ((x >> 16) & 1u)) >> 16;
  return (ushort_t)r;
}
__device__ __forceinline__ float b2f(ushort_t u) {
  return __uint_as_float(((unsigned int)u) << 16);
}

// ---------------- K0: convert weights to bf16, concatenated ----------------
// Wcat order: 0:Wga 1:Wa 2:Wgb 3:Wb 4:Wog 5:Wo
__global__ __launch_bounds__(256) void k_wconv(
    const float* __restrict__ Wga, const float* __restrict__ Wa,
    const float* __restrict__ Wgb, const float* __restrict__ Wb,
    const float* __restrict__ Wog, const float* __restrict__ Wo,
    ushort_t* __restrict__ Wcat) {
  int idx = blockIdx.x * 256 + threadIdx.x;  // 6*16384 total
  const float* srcs[6] = {Wga, Wa, Wgb, Wb, Wog, Wo};
  float v = srcs[idx >> 14][idx & 16383];
  Wcat[idx] = f2b(v);
}

// ---------------- K1: layernorm -> zn bf16 row-major [m][c] ----------------
__global__ __launch_bounds__(256) void k_ln(
    const float* __restrict__ z, const float* __restrict__ gamma,
    const float* __restrict__ beta, ushort_t* __restrict__ zn) {
  int lane = threadIdx.x & 63;
  size_t m = (size_t)blockIdx.x * 4 + (threadIdx.x >> 6);
  float2 v = *reinterpret_cast<const float2*>(z + m * CZ + lane * 2);
  float s = v.x + v.y, ss = v.x * v.x + v.y * v.y;
#pragma unroll
  for (int o = 32; o; o >>= 1) { s += __shfl_xor(s, o); ss += __shfl_xor(ss, o); }
  float mu = s * (1.0f / CZ);
  float var = fmaxf(ss * (1.0f / CZ) - mu * mu, 0.0f);
  float inv = rsqrtf(var + 1e-5f);
  float2 g = *reinterpret_cast<const float2*>(gamma + lane * 2);
  float2 b = *reinterpret_cast<const float2*>(beta + lane * 2);
  ushort_t o0 = f2b((v.x - mu) * inv * g.x + b.x);
  ushort_t o1 = f2b((v.y - mu) * inv * g.y + b.y);
  unsigned int packed = (unsigned int)o0 | ((unsigned int)o1 << 16);
  *reinterpret_cast<unsigned int*>(zn + m * CZ + lane * 2) = packed;
}

// ---------------- K2: projections P = W * zn^T (5 matmuls in 3 types) -----
// type 0: a = sigmoid(Wga zn + bga) * (Wa zn + ba) -> a_cm [c][m]
// type 1: b -> b_cm [c][m]
// type 2: og = sigmoid(Wog zn + bog) -> og_rm [m][c] (LDS transpose)
__global__ __launch_bounds__(256) void k_proj(
    const ushort_t* __restrict__ zn, const ushort_t* __restrict__ Wcat,
    const float* __restrict__ bga, const float* __restrict__ ba,
    const float* __restrict__ bgb, const float* __restrict__ bb,
    const float* __restrict__ bog,
    ushort_t* __restrict__ a_cm, ushort_t* __restrict__ b_cm,
    ushort_t* __restrict__ og_rm) {
  __shared__ ushort_t lds[64 * 136];
  const int t = threadIdx.x;
  const int type = blockIdx.y;
  const int m0 = blockIdx.x * 64;
  // stage zn tile [64 m][128 k] into LDS (stride 136, pad 8)
#pragma unroll
  for (int p = 0; p < 4; p++) {
    int lin = p * 256 + t;
    int row = lin >> 4, ch = lin & 15;
    *reinterpret_cast<short8*>(&lds[row * 136 + ch * 8]) =
        *reinterpret_cast<const short8*>(zn + (size_t)(m0 + row) * CZ + ch * 8);
  }
  __syncthreads();
  const int wid = t >> 6, lane = t & 63, lr = lane & 15, lq = lane >> 4;
  const int wm = (wid & 1) * 32, wc = (wid >> 1) * 64;
  const ushort_t* Wg = Wcat + (size_t)(type == 0 ? 0 : type == 1 ? 2 : 4) * 16384;
  const ushort_t* Wv = Wcat + (size_t)(type == 0 ? 1 : 3) * 16384;
  f32x4 accG[4][2], accV[4][2];
#pragma unroll
  for (int cs = 0; cs < 4; cs++)
#pragma unroll
    for (int ms = 0; ms < 2; ms++) {
      accG[cs][ms] = (f32x4){0.f, 0.f, 0.f, 0.f};
      accV[cs][ms] = (f32x4){0.f, 0.f, 0.f, 0.f};
    }
#pragma unroll
  for (int kk = 0; kk < 128; kk += 32) {
    short8 bfr[2];
#pragma unroll
    for (int ms = 0; ms < 2; ms++)
      bfr[ms] = *reinterpret_cast<const short8*>(
          &lds[(wm + ms * 16 + lr) * 136 + kk + lq * 8]);
#pragma unroll
    for (int cs = 0; cs < 4; cs++) {
      short8 ag = *reinterpret_cast<const short8*>(
          Wg + (size_t)(wc + cs * 16 + lr) * CZ + kk + lq * 8);
#pragma unroll
      for (int ms = 0; ms < 2; ms++)
        accG[cs][ms] = __builtin_amdgcn_mfma_f32_16x16x32_bf16(
            ag, bfr[ms], accG[cs][ms], 0, 0, 0);
      if (type < 2) {
        short8 av = *reinterpret_cast<const short8*>(
            Wv + (size_t)(wc + cs * 16 + lr) * CZ + kk + lq * 8);
#pragma unroll
        for (int ms = 0; ms < 2; ms++)
          accV[cs][ms] = __builtin_amdgcn_mfma_f32_16x16x32_bf16(
              av, bfr[ms], accV[cs][ms], 0, 0, 0);
      }
    }
  }
  if (type < 2) {
    const float* bg = (type == 0) ? bga : bgb;
    const float* bv = (type == 0) ? ba : bb;
    ushort_t* outp = (type == 0) ? a_cm : b_cm;
#pragma unroll
    for (int cs = 0; cs < 4; cs++)
#pragma unroll
      for (int ms = 0; ms < 2; ms++)
#pragma unroll
        for (int r = 0; r < 4; r++) {
          int c = wc + cs * 16 + lq * 4 + r;
          int m = m0 + wm + ms * 16 + lr;
          float gg = accG[cs][ms][r] + bg[c];
          float vv = accV[cs][ms][r] + bv[c];
          float val = vv / (1.0f + __expf(-gg));
          outp[(size_t)c * NN + m] = f2b(val);
        }
  } else {
    __syncthreads();  // done with zn tile; reuse LDS as [64 m][128 c] transpose buffer
#pragma unroll
    for (int cs = 0; cs < 4; cs++)
#pragma unroll
      for (int ms = 0; ms < 2; ms++)
#pragma unroll
        for (int r = 0; r < 4; r++) {
          int c = wc + cs * 16 + lq * 4 + r;
          int ml = wm + ms * 16 + lr;
          float gg = accG[cs][ms][r] + bog[c];
          lds[ml * 136 + c] = f2b(1.0f / (1.0f + __expf(-gg)));
        }
    __syncthreads();
    int row = t >> 2, ch = t & 3;
#pragma unroll
    for (int j = 0; j < 4; j++) {
      *reinterpret_cast<short8*>(og_rm + (size_t)(m0 + row) * CZ + ch * 32 + j * 8) =
          *reinterpret_cast<const short8*>(&lds[row * 136 + ch * 32 + j * 8]);
    }
  }
}

// ---------------- K3: per-channel einsum U_c = A_c * B_c^T ----------------
// a_cm/b_cm/u_cm are [c][i*N+k] channel-major bf16.
__global__ __launch_bounds__(256) void k_tri(
    const ushort_t* __restrict__ a_cm, const ushort_t* __restrict__ b_cm,
    ushort_t* __restrict__ u_cm) {
  __shared__ ushort_t lA[128 * 72];
  __shared__ ushort_t lB[128 * 72];
  const int t = threadIdx.x;
  const int i0 = blockIdx.x * 128, j0 = blockIdx.y * 128;
  const size_t base = (size_t)blockIdx.z * NN;
  const int wid = t >> 6, lane = t & 63, lr = lane & 15, lq = lane >> 4;
  const int wi = (wid >> 1) * 64, wj = (wid & 1) * 64;
  f32x4 acc[4][4];
#pragma unroll
  for (int si = 0; si < 4; si++)
#pragma unroll
    for (int sj = 0; sj < 4; sj++) acc[si][sj] = (f32x4){0.f, 0.f, 0.f, 0.f};

  for (int kb = 0; kb < 8; kb++) {
    const int k0 = kb * 64;
#pragma unroll
    for (int p = 0; p < 4; p++) {
      int lin = p * 256 + t;
      int row = lin >> 3, ch = lin & 7;
      *reinterpret_cast<short8*>(&lA[row * 72 + ch * 8]) =
          *reinterpret_cast<const short8*>(a_cm + base + (size_t)(i0 + row) * NDIM + k0 + ch * 8);
      *reinterpret_cast<short8*>(&lB[row * 72 + ch * 8]) =
          *reinterpret_cast<const short8*>(b_cm + base + (size_t)(j0 + row) * NDIM + k0 + ch * 8);
    }
    __syncthreads();
#pragma unroll
    for (int ks = 0; ks < 2; ks++) {
      short8 af[4], bf[4];
#pragma unroll
      for (int s = 0; s < 4; s++) {
        af[s] = *reinterpret_cast<const short8*>(&lA[(wi + s * 16 + lr) * 72 + ks * 32 + lq * 8]);
        bf[s] = *reinterpret_cast<const short8*>(&lB[(wj + s * 16 + lr) * 72 + ks * 32 + lq * 8]);
      }
#pragma unroll
      for (int si = 0; si < 4; si++)
#pragma unroll
        for (int sj = 0; sj < 4; sj++)
          acc[si][sj] = __builtin_amdgcn_mfma_f32_16x16x32_bf16(
              af[si], bf[sj], acc[si][sj], 0, 0, 0);
    }
    __syncthreads();
  }
#pragma unroll
  for (int si = 0; si < 4; si++)
#pragma unroll
    for (int sj = 0; sj < 4; sj++)
#pragma unroll
      for (int r = 0; r < 4; r++) {
        int i = i0 + wi + si * 16 + lq * 4 + r;
        int j = j0 + wj + sj * 16 + lr;
        u_cm[base + (size_t)i * NDIM + j] = f2b(acc[si][sj][r]);
      }
}

// ---------------- K4: out = z + og * (U^T Wo^T + bo) ----------------------
__global__ __launch_bounds__(256) void k_out(
    const ushort_t* __restrict__ u_cm, const ushort_t* __restrict__ WoB,
    const ushort_t* __restrict__ og_rm, const float* __restrict__ z,
    const float* __restrict__ bo, float* __restrict__ out) {
  __shared__ ushort_t lu[128 * 136];  // [c][m-tile], stride 136
  const int t = threadIdx.x;
  const int m0 = blockIdx.x * 128;
#pragma unroll
  for (int p = 0; p < 8; p++) {
    int lin = p * 256 + t;
    int cr = lin >> 4, ch = lin & 15;
    *reinterpret_cast<short8*>(&lu[cr * 136 + ch * 8]) =
        *reinterpret_cast<const short8*>(u_cm + (size_t)cr * NN + m0 + ch * 8);
  }
  __syncthreads();
  const int wid = t >> 6, lane = t & 63, lr = lane & 15, lq = lane >> 4;
  const int wm = (wid >> 1) * 64, wc = (wid & 1) * 64;
  f32x4 acc[4][4];
#pragma unroll
  for (int ms = 0; ms < 4; ms++)
#pragma unroll
    for (int cs = 0; cs < 4; cs++) acc[ms][cs] = (f32x4){0.f, 0.f, 0.f, 0.f};
#pragma unroll
  for (int kk = 0; kk < 128; kk += 32) {
    short8 af[4];
#pragma unroll
    for (int ms = 0; ms < 4; ms++) {
      short8 v;
#pragma unroll
      for (int jj = 0; jj < 8; jj++)
        v[jj] = (short)lu[(kk + lq * 8 + jj) * 136 + wm + ms * 16 + lr];
      af[ms] = v;
    }
#pragma unroll
    for (int cs = 0; cs < 4; cs++) {
      short8 bf = *reinterpret_cast<const short8*>(
          WoB + (size_t)(wc + cs * 16 + lr) * CZ + kk + lq * 8);
#pragma unroll
      for (int ms = 0; ms < 4; ms++)
        acc[ms][cs] = __builtin_amdgcn_mfma_f32_16x16x32_bf16(
            af[ms], bf, acc[ms][cs], 0, 0, 0);
    }
  }
#pragma unroll
  for (int ms = 0; ms < 4; ms++)
#pragma unroll
    for (int cs = 0; cs < 4; cs++)
#pragma unroll
      for (int r = 0; r < 4; r++) {
        int m = m0 + wm + ms * 16 + lq * 4 + r;
        int cp = wc + cs * 16 + lr;
        float val = acc[ms][cs][r] + bo[cp];
        float gate = b2f(og_rm[(size_t)m * CZ + cp]);
        out[(size_t)m * CZ + cp] = z[(size_t)m * CZ + cp] + gate * val;
      }
}

extern "C" void kernel_launch(void* const* d_in, const int* in_sizes, int n_in,
                              void* d_out, int out_size, void* d_ws, size_t ws_size,
                              hipStream_t stream) {
  const float* z = (const float*)d_in[0];
  const float* gamma = (const float*)d_in[1];
  const float* beta = (const float*)d_in[2];
  const float* Wa = (const float*)d_in[3];  const float* ba = (const float*)d_in[4];
  const float* Wb = (const float*)d_in[5];  const float* bb = (const float*)d_in[6];
  const float* Wga = (const float*)d_in[7]; const float* bga = (const float*)d_in[8];
  const float* Wgb = (const float*)d_in[9]; const float* bgb = (const float*)d_in[10];
  const float* Wo = (const float*)d_in[11]; const float* bo = (const float*)d_in[12];
  const float* Wog = (const float*)d_in[13];const float* bog = (const float*)d_in[14];

  char* ws = (char*)d_ws;
  ushort_t* a_cm = (ushort_t*)(ws);                     // 64 MiB [c][m]
  ushort_t* b_cm = (ushort_t*)(ws + 67108864);          // 64 MiB [c][m]
  ushort_t* og_rm = (ushort_t*)(ws + 134217728);        // 64 MiB [m][c]
  ushort_t* zn = (ushort_t*)(ws + 201326592);           // 64 MiB [m][c]; reused as u_cm
  ushort_t* u_cm = zn;                                  // zn dead after k_proj
  ushort_t* Wcat = (ushort_t*)(ws + 268435456);         // 192 KiB

  k_wconv<<<384, 256, 0, stream>>>(Wga, Wa, Wgb, Wb, Wog, Wo, Wcat);
  k_ln<<<NN / 4, 256, 0, stream>>>(z, gamma, beta, zn);
  dim3 g2(NN / 64, 3);
  k_proj<<<g2, 256, 0, stream>>>(zn, Wcat, bga, ba, bgb, bb, bog, a_cm, b_cm, og_rm);
  dim3 g3(4, 4, 128);
  k_tri<<<g3, 256, 0, stream>>>(a_cm, b_cm, u_cm);
  k_out<<<NN / 128, 256, 0, stream>>>(u_cm, Wcat + 5 * 16384, og_rm, z, bo, (float*)d_out);
}

// Round 2
// 521.020 us; speedup vs baseline: 1.0042x; 1.0042x over previous
//
#include <hip/hip_runtime.h>

#define NDIM 512
#define CZ 128
#define NN (NDIM*NDIM)

typedef __attribute__((ext_vector_type(8))) short short8;
typedef __attribute__((ext_vector_type(4))) float f32x4;
typedef unsigned short ushort_t;

__device__ __forceinline__ ushort_t f2b(float f) {
  unsigned int x = __float_as_uint(f);
  unsigned int r = (x + 0x7fffu + ((x >> 16) & 1u)) >> 16;
  return (ushort_t)r;
}
__device__ __forceinline__ float b2f(ushort_t u) {
  return __uint_as_float(((unsigned int)u) << 16);
}

// ---------------- K0: convert weights to bf16, concatenated ----------------
// Wcat order: 0:Wga 1:Wa 2:Wgb 3:Wb 4:Wog 5:Wo
__global__ __launch_bounds__(256) void k_wconv(
    const float* __restrict__ Wga, const float* __restrict__ Wa,
    const float* __restrict__ Wgb, const float* __restrict__ Wb,
    const float* __restrict__ Wog, const float* __restrict__ Wo,
    ushort_t* __restrict__ Wcat) {
  int idx = blockIdx.x * 256 + threadIdx.x;  // 6*16384 total
  const float* srcs[6] = {Wga, Wa, Wgb, Wb, Wog, Wo};
  float v = srcs[idx >> 14][idx & 16383];
  Wcat[idx] = f2b(v);
}

// ---------------- K1: layernorm -> zn bf16 row-major [m][c] ----------------
__global__ __launch_bounds__(256) void k_ln(
    const float* __restrict__ z, const float* __restrict__ gamma,
    const float* __restrict__ beta, ushort_t* __restrict__ zn) {
  int lane = threadIdx.x & 63;
  size_t m = (size_t)blockIdx.x * 4 + (threadIdx.x >> 6);
  float2 v = *reinterpret_cast<const float2*>(z + m * CZ + lane * 2);
  float s = v.x + v.y, ss = v.x * v.x + v.y * v.y;
#pragma unroll
  for (int o = 32; o; o >>= 1) { s += __shfl_xor(s, o); ss += __shfl_xor(ss, o); }
  float mu = s * (1.0f / CZ);
  float var = fmaxf(ss * (1.0f / CZ) - mu * mu, 0.0f);
  float inv = rsqrtf(var + 1e-5f);
  float2 g = *reinterpret_cast<const float2*>(gamma + lane * 2);
  float2 b = *reinterpret_cast<const float2*>(beta + lane * 2);
  ushort_t o0 = f2b((v.x - mu) * inv * g.x + b.x);
  ushort_t o1 = f2b((v.y - mu) * inv * g.y + b.y);
  unsigned int packed = (unsigned int)o0 | ((unsigned int)o1 << 16);
  *reinterpret_cast<unsigned int*>(zn + m * CZ + lane * 2) = packed;
}

// ---------------- K2: projections P = W * zn^T (5 matmuls in 3 types) -----
// type 0: a = sigmoid(Wga zn + bga) * (Wa zn + ba) -> a_cm [c][m]
// type 1: b -> b_cm [c][m]
// type 2: og = sigmoid(Wog zn + bog) -> og_rm [m][c] (LDS transpose)
__global__ __launch_bounds__(256) void k_proj(
    const ushort_t* __restrict__ zn, const ushort_t* __restrict__ Wcat,
    const float* __restrict__ bga, const float* __restrict__ ba,
    const float* __restrict__ bgb, const float* __restrict__ bb,
    const float* __restrict__ bog,
    ushort_t* __restrict__ a_cm, ushort_t* __restrict__ b_cm,
    ushort_t* __restrict__ og_rm) {
  __shared__ ushort_t zt[64 * 136];   // zn tile [64 m][128 k], stride 136
  __shared__ ushort_t ot[128 * 72];   // output staging [128 c][64 m], stride 72
  const int t = threadIdx.x;
  const int type = blockIdx.y;
  const int m0 = blockIdx.x * 64;
#pragma unroll
  for (int p = 0; p < 4; p++) {
    int lin = p * 256 + t;
    int row = lin >> 4, ch = lin & 15;
    *reinterpret_cast<short8*>(&zt[row * 136 + ch * 8]) =
        *reinterpret_cast<const short8*>(zn + (size_t)(m0 + row) * CZ + ch * 8);
  }
  __syncthreads();
  const int wid = t >> 6, lane = t & 63, lr = lane & 15, lq = lane >> 4;
  const int wm = (wid & 1) * 32, wc = (wid >> 1) * 64;
  const ushort_t* Wg = Wcat + (size_t)(type == 0 ? 0 : type == 1 ? 2 : 4) * 16384;
  const ushort_t* Wv = Wcat + (size_t)(type == 0 ? 1 : 3) * 16384;
  f32x4 accG[4][2], accV[4][2];
#pragma unroll
  for (int cs = 0; cs < 4; cs++)
#pragma unroll
    for (int ms = 0; ms < 2; ms++) {
      accG[cs][ms] = (f32x4){0.f, 0.f, 0.f, 0.f};
      accV[cs][ms] = (f32x4){0.f, 0.f, 0.f, 0.f};
    }
#pragma unroll
  for (int kk = 0; kk < 128; kk += 32) {
    short8 bfr[2];
#pragma unroll
    for (int ms = 0; ms < 2; ms++)
      bfr[ms] = *reinterpret_cast<const short8*>(
          &zt[(wm + ms * 16 + lr) * 136 + kk + lq * 8]);
#pragma unroll
    for (int cs = 0; cs < 4; cs++) {
      short8 ag = *reinterpret_cast<const short8*>(
          Wg + (size_t)(wc + cs * 16 + lr) * CZ + kk + lq * 8);
#pragma unroll
      for (int ms = 0; ms < 2; ms++)
        accG[cs][ms] = __builtin_amdgcn_mfma_f32_16x16x32_bf16(
            ag, bfr[ms], accG[cs][ms], 0, 0, 0);
      if (type < 2) {
        short8 av = *reinterpret_cast<const short8*>(
            Wv + (size_t)(wc + cs * 16 + lr) * CZ + kk + lq * 8);
#pragma unroll
        for (int ms = 0; ms < 2; ms++)
          accV[cs][ms] = __builtin_amdgcn_mfma_f32_16x16x32_bf16(
              av, bfr[ms], accV[cs][ms], 0, 0, 0);
      }
    }
  }
  if (type < 2) {
    const float* bg = (type == 0) ? bga : bgb;
    const float* bv = (type == 0) ? ba : bb;
    ushort_t* outp = (type == 0) ? a_cm : b_cm;
    // epilogue -> LDS staging [c][m]
#pragma unroll
    for (int cs = 0; cs < 4; cs++)
#pragma unroll
      for (int ms = 0; ms < 2; ms++)
#pragma unroll
        for (int r = 0; r < 4; r++) {
          int c = wc + cs * 16 + lq * 4 + r;
          int ml = wm + ms * 16 + lr;
          float gg = accG[cs][ms][r] + bg[c];
          float vv = accV[cs][ms][r] + bv[c];
          ot[c * 72 + ml] = f2b(vv / (1.0f + __expf(-gg)));
        }
    __syncthreads();
    // coalesced vectorized store: 128 c rows x 64 m
#pragma unroll
    for (int p = 0; p < 4; p++) {
      int lin = p * 256 + t;
      int c = lin >> 3, mc = (lin & 7) * 8;
      *reinterpret_cast<short8*>(outp + (size_t)c * NN + m0 + mc) =
          *reinterpret_cast<const short8*>(&ot[c * 72 + mc]);
    }
  } else {
    __syncthreads();  // done with zn tile; reuse zt as [64 m][128 c] transpose buffer
#pragma unroll
    for (int cs = 0; cs < 4; cs++)
#pragma unroll
      for (int ms = 0; ms < 2; ms++)
#pragma unroll
        for (int r = 0; r < 4; r++) {
          int c = wc + cs * 16 + lq * 4 + r;
          int ml = wm + ms * 16 + lr;
          float gg = accG[cs][ms][r] + bog[c];
          zt[ml * 136 + c] = f2b(1.0f / (1.0f + __expf(-gg)));
        }
    __syncthreads();
    int row = t >> 2, ch = t & 3;
#pragma unroll
    for (int j = 0; j < 4; j++) {
      *reinterpret_cast<short8*>(og_rm + (size_t)(m0 + row) * CZ + ch * 32 + j * 8) =
          *reinterpret_cast<const short8*>(&zt[row * 136 + ch * 32 + j * 8]);
    }
  }
}

// ---------------- K3: per-channel einsum U_c = A_c * B_c^T ----------------
// a_cm/b_cm/u_cm are [c][i*N+k] channel-major bf16.
__global__ __launch_bounds__(256) void k_tri(
    const ushort_t* __restrict__ a_cm, const ushort_t* __restrict__ b_cm,
    ushort_t* __restrict__ u_cm) {
  __shared__ ushort_t sh[18432];  // lA[128*72] + lB[128*72]; reused as out[128*136]
  ushort_t* lA = sh;
  ushort_t* lB = sh + 9216;
  const int t = threadIdx.x;
  const int i0 = blockIdx.x * 128, j0 = blockIdx.y * 128;
  const size_t base = (size_t)blockIdx.z * NN;
  const int wid = t >> 6, lane = t & 63, lr = lane & 15, lq = lane >> 4;
  const int wi = (wid >> 1) * 64, wj = (wid & 1) * 64;
  f32x4 acc[4][4];
#pragma unroll
  for (int si = 0; si < 4; si++)
#pragma unroll
    for (int sj = 0; sj < 4; sj++) acc[si][sj] = (f32x4){0.f, 0.f, 0.f, 0.f};

  for (int kb = 0; kb < 8; kb++) {
    const int k0 = kb * 64;
#pragma unroll
    for (int p = 0; p < 4; p++) {
      int lin = p * 256 + t;
      int row = lin >> 3, ch = lin & 7;
      *reinterpret_cast<short8*>(&lA[row * 72 + ch * 8]) =
          *reinterpret_cast<const short8*>(a_cm + base + (size_t)(i0 + row) * NDIM + k0 + ch * 8);
      *reinterpret_cast<short8*>(&lB[row * 72 + ch * 8]) =
          *reinterpret_cast<const short8*>(b_cm + base + (size_t)(j0 + row) * NDIM + k0 + ch * 8);
    }
    __syncthreads();
#pragma unroll
    for (int ks = 0; ks < 2; ks++) {
      short8 af[4], bf[4];
#pragma unroll
      for (int s = 0; s < 4; s++) {
        af[s] = *reinterpret_cast<const short8*>(&lA[(wi + s * 16 + lr) * 72 + ks * 32 + lq * 8]);
        bf[s] = *reinterpret_cast<const short8*>(&lB[(wj + s * 16 + lr) * 72 + ks * 32 + lq * 8]);
      }
#pragma unroll
      for (int si = 0; si < 4; si++)
#pragma unroll
        for (int sj = 0; sj < 4; sj++)
          acc[si][sj] = __builtin_amdgcn_mfma_f32_16x16x32_bf16(
              af[si], bf[sj], acc[si][sj], 0, 0, 0);
    }
    __syncthreads();
  }
  // epilogue -> LDS staging [128 i][128 j], stride 136
#pragma unroll
  for (int si = 0; si < 4; si++)
#pragma unroll
    for (int sj = 0; sj < 4; sj++)
#pragma unroll
      for (int r = 0; r < 4; r++) {
        int il = wi + si * 16 + lq * 4 + r;
        int jl = wj + sj * 16 + lr;
        sh[il * 136 + jl] = f2b(acc[si][sj][r]);
      }
  __syncthreads();
  // coalesced vectorized store
#pragma unroll
  for (int p = 0; p < 8; p++) {
    int lin = p * 256 + t;
    int row = lin >> 4, col = (lin & 15) * 8;
    *reinterpret_cast<short8*>(u_cm + base + (size_t)(i0 + row) * NDIM + j0 + col) =
        *reinterpret_cast<const short8*>(&sh[row * 136 + col]);
  }
}

// ---------------- K4: out = z + og * (U^T Wo^T + bo) ----------------------
__global__ __launch_bounds__(256) void k_out(
    const ushort_t* __restrict__ u_cm, const ushort_t* __restrict__ WoB,
    const ushort_t* __restrict__ og_rm, const float* __restrict__ z,
    const float* __restrict__ bo, float* __restrict__ out) {
  __shared__ ushort_t lu[128 * 136];  // [c][m-tile], stride 136
  const int t = threadIdx.x;
  const int m0 = blockIdx.x * 128;
#pragma unroll
  for (int p = 0; p < 8; p++) {
    int lin = p * 256 + t;
    int cr = lin >> 4, ch = lin & 15;
    *reinterpret_cast<short8*>(&lu[cr * 136 + ch * 8]) =
        *reinterpret_cast<const short8*>(u_cm + (size_t)cr * NN + m0 + ch * 8);
  }
  __syncthreads();
  const int wid = t >> 6, lane = t & 63, lr = lane & 15, lq = lane >> 4;
  const int wm = (wid >> 1) * 64, wc = (wid & 1) * 64;
  f32x4 acc[4][4];
#pragma unroll
  for (int ms = 0; ms < 4; ms++)
#pragma unroll
    for (int cs = 0; cs < 4; cs++) acc[ms][cs] = (f32x4){0.f, 0.f, 0.f, 0.f};
#pragma unroll
  for (int kk = 0; kk < 128; kk += 32) {
    short8 af[4];
#pragma unroll
    for (int ms = 0; ms < 4; ms++) {
      short8 v;
#pragma unroll
      for (int jj = 0; jj < 8; jj++)
        v[jj] = (short)lu[(kk + lq * 8 + jj) * 136 + wm + ms * 16 + lr];
      af[ms] = v;
    }
#pragma unroll
    for (int cs = 0; cs < 4; cs++) {
      short8 bf = *reinterpret_cast<const short8*>(
          WoB + (size_t)(wc + cs * 16 + lr) * CZ + kk + lq * 8);
#pragma unroll
      for (int ms = 0; ms < 4; ms++)
        acc[ms][cs] = __builtin_amdgcn_mfma_f32_16x16x32_bf16(
            af[ms], bf, acc[ms][cs], 0, 0, 0);
    }
  }
#pragma unroll
  for (int ms = 0; ms < 4; ms++)
#pragma unroll
    for (int cs = 0; cs < 4; cs++)
#pragma unroll
      for (int r = 0; r < 4; r++) {
        int m = m0 + wm + ms * 16 + lq * 4 + r;
        int cp = wc + cs * 16 + lr;
        float val = acc[ms][cs][r] + bo[cp];
        float gate = b2f(og_rm[(size_t)m * CZ + cp]);
        out[(size_t)m * CZ + cp] = z[(size_t)m * CZ + cp] + gate * val;
      }
}

extern "C" void kernel_launch(void* const* d_in, const int* in_sizes, int n_in,
                              void* d_out, int out_size, void* d_ws, size_t ws_size,
                              hipStream_t stream) {
  const float* z = (const float*)d_in[0];
  const float* gamma = (const float*)d_in[1];
  const float* beta = (const float*)d_in[2];
  const float* Wa = (const float*)d_in[3];  const float* ba = (const float*)d_in[4];
  const float* Wb = (const float*)d_in[5];  const float* bb = (const float*)d_in[6];
  const float* Wga = (const float*)d_in[7]; const float* bga = (const float*)d_in[8];
  const float* Wgb = (const float*)d_in[9]; const float* bgb = (const float*)d_in[10];
  const float* Wo = (const float*)d_in[11]; const float* bo = (const float*)d_in[12];
  const float* Wog = (const float*)d_in[13];const float* bog = (const float*)d_in[14];

  char* ws = (char*)d_ws;
  ushort_t* a_cm = (ushort_t*)(ws);                     // 64 MiB [c][m]
  ushort_t* b_cm = (ushort_t*)(ws + 67108864);          // 64 MiB [c][m]
  ushort_t* og_rm = (ushort_t*)(ws + 134217728);        // 64 MiB [m][c]
  ushort_t* zn = (ushort_t*)(ws + 201326592);           // 64 MiB [m][c]; reused as u_cm
  ushort_t* u_cm = zn;                                  // zn dead after k_proj
  ushort_t* Wcat = (ushort_t*)(ws + 268435456);         // 192 KiB

  k_wconv<<<384, 256, 0, stream>>>(Wga, Wa, Wgb, Wb, Wog, Wo, Wcat);
  k_ln<<<NN / 4, 256, 0, stream>>>(z, gamma, beta, zn);
  dim3 g2(NN / 64, 3);
  k_proj<<<g2, 256, 0, stream>>>(zn, Wcat, bga, ba, bgb, bb, bog, a_cm, b_cm, og_rm);
  dim3 g3(4, 4, 128);
  k_tri<<<g3, 256, 0, stream>>>(a_cm, b_cm, u_cm);
  k_out<<<NN / 128, 256, 0, stream>>>(u_cm, Wcat + 5 * 16384, og_rm, z, bo, (float*)d_out);
}